// Round 10
// baseline (19.193 us; speedup 1.0000x reference)
//
#include <hip/hip_runtime.h>

#define NROWS  65536
#define NCLS   256
#define NBLK   2048
#define NLINE  64              // partial-sum lines; NBLK/NLINE = 32 blocks each
#define BPL    (NBLK / NLINE)

typedef float nt_f4 __attribute__((ext_vector_type(4)));

// Device-global finish state. Zero at module load; every call resets it to
// zero => deterministic across graph replays, immune to d_ws poisoning.
// NO fences: ordering comes from completed returning atomics only (R6-proven).
struct __align__(128) Line { float v; int cnt; int pad[30]; };
__device__ Line g_line[NLINE];
__device__ int  g_master;

__global__ __launch_bounds__(256) void OrdinalLoss_main_kernel(
    const float* __restrict__ pred, const int* __restrict__ tgt,
    float* __restrict__ out, int nrows)
{
    const int tid    = blockIdx.x * blockDim.x + threadIdx.x;
    const int lane   = threadIdx.x & 63;
    const int g      = lane >> 4;        // row within 4-row pack
    const int li     = lane & 15;        // lane within 16-lane row group
    const int wave   = tid >> 6;
    const int nwaves = (gridDim.x * blockDim.x) >> 6;

    float acc = 0.0f;
    const float j0 = (float)(li * 4);

    #define TERM(S0, S1, S2, PV, OFF) {                                     \
        const float d = j0 + (float)(OFF);                                  \
        const float e = __expf(PV);                                         \
        S0 += e;                                                            \
        const float t1 = e * d;                                             \
        S1 += t1;                                                           \
        S2 = fmaf(t1, d, S2); }
    #define PACK16(S0, S1, S2, Q0, Q1, Q2, Q3)                              \
        TERM(S0,S1,S2, Q0[0],   0) TERM(S0,S1,S2, Q0[1],   1)               \
        TERM(S0,S1,S2, Q0[2],   2) TERM(S0,S1,S2, Q0[3],   3)               \
        TERM(S0,S1,S2, Q1[0],  64) TERM(S0,S1,S2, Q1[1],  65)               \
        TERM(S0,S1,S2, Q1[2],  66) TERM(S0,S1,S2, Q1[3],  67)               \
        TERM(S0,S1,S2, Q2[0], 128) TERM(S0,S1,S2, Q2[1], 129)               \
        TERM(S0,S1,S2, Q2[2], 130) TERM(S0,S1,S2, Q2[3], 131)               \
        TERM(S0,S1,S2, Q3[0], 192) TERM(S0,S1,S2, Q3[1], 193)               \
        TERM(S0,S1,S2, Q3[2], 194) TERM(S0,S1,S2, Q3[3], 195)

    #define PT(PTV, T, Q0, Q1, Q2, Q3) {                                    \
        const int q = (T) >> 6, r = (T) & 3;                                \
        const nt_f4 Q = (q==0) ? Q0 : (q==1) ? Q1 : (q==2) ? Q2 : Q3;       \
        const float pv = (r==0) ? Q[0] : (r==1) ? Q[1] : (r==2) ? Q[2] : Q[3]; \
        PTV = (li == (((T) >> 2) & 15)) ? pv : 0.0f; }

    #define REDUCE4(S0, S1, S2, PTV, T)                                     \
        _Pragma("unroll")                                                   \
        for (int m = 8; m; m >>= 1) {                                       \
            S0 += __shfl_xor(S0, m); S1 += __shfl_xor(S1, m);               \
            S2 += __shfl_xor(S2, m); PTV += __shfl_xor(PTV, m);             \
        }                                                                   \
        if (li == 0) {                                                      \
            const float tf = (float)(T);                                    \
            acc += __logf(S0) - PTV                                         \
                 + (S2 - 2.0f * tf * S1 + tf * tf * S0) / S0;               \
        }

    // policy-split load: first half of the buffer via regular loads (stays
    // L3-resident across replays), second half via NT (streams from HBM,
    // no-allocate => never evicts the resident half). Both paths in flight.
    #define LOADPACK(D0, D1, D2, D3, RP, PK, SPLIT)                         \
        nt_f4 D0, D1, D2, D3;                                               \
        if ((PK) < (SPLIT)) {                                               \
            D0 = *reinterpret_cast<const nt_f4*>(RP);                       \
            D1 = *reinterpret_cast<const nt_f4*>((RP) + 64);                \
            D2 = *reinterpret_cast<const nt_f4*>((RP) + 128);               \
            D3 = *reinterpret_cast<const nt_f4*>((RP) + 192);               \
        } else {                                                            \
            D0 = __builtin_nontemporal_load((const nt_f4*)(RP));            \
            D1 = __builtin_nontemporal_load((const nt_f4*)((RP) + 64));     \
            D2 = __builtin_nontemporal_load((const nt_f4*)((RP) + 128));    \
            D3 = __builtin_nontemporal_load((const nt_f4*)((RP) + 192));    \
        }

    const int npacks = nrows >> 2;
    const int split  = npacks >> 1;      // first half regular, second half NT
    int pack = wave;
    // dual-pack iteration: with nwaves == npacks/2 this runs exactly once,
    // pack A in the regular half, pack B in the NT half — both paths busy.
    for (; pack + nwaves < npacks; pack += 2 * nwaves) {
        const int packB = pack + nwaves;
        const int rowA = pack  * 4 + g;
        const int rowB = packB * 4 + g;
        const float* rpA = pred + (size_t)rowA * NCLS + li * 4;
        const float* rpB = pred + (size_t)rowB * NCLS + li * 4;
        LOADPACK(a0, a1, a2, a3, rpA, pack,  split)
        LOADPACK(b0, b1, b2, b3, rpB, packB, split)
        const int tA = tgt[rowA];
        const int tB = tgt[rowB];

        float sA0 = 0.0f, sA1 = 0.0f, sA2 = 0.0f, ptA;
        PACK16(sA0, sA1, sA2, a0, a1, a2, a3)
        PT(ptA, tA, a0, a1, a2, a3)
        REDUCE4(sA0, sA1, sA2, ptA, tA)

        float sB0 = 0.0f, sB1 = 0.0f, sB2 = 0.0f, ptB;
        PACK16(sB0, sB1, sB2, b0, b1, b2, b3)
        PT(ptB, tB, b0, b1, b2, b3)
        REDUCE4(sB0, sB1, sB2, ptB, tB)
    }
    // tail: single pack
    if (pack < npacks) {
        const int rowA = pack * 4 + g;
        const float* rpA = pred + (size_t)rowA * NCLS + li * 4;
        LOADPACK(a0, a1, a2, a3, rpA, pack, split)
        const int tA = tgt[rowA];
        float sA0 = 0.0f, sA1 = 0.0f, sA2 = 0.0f, ptA;
        PACK16(sA0, sA1, sA2, a0, a1, a2, a3)
        PT(ptA, tA, a0, a1, a2, a3)
        REDUCE4(sA0, sA1, sA2, ptA, tA)
    }
    #undef TERM
    #undef PACK16
    #undef PT
    #undef REDUCE4
    #undef LOADPACK

    // ---- block reduce ----
    __shared__ float red[256];
    __shared__ int amLast;
    red[threadIdx.x] = acc;
    __syncthreads();
    float v = 0.0f;
    if (threadIdx.x < 64) {
        v = red[threadIdx.x] + red[threadIdx.x + 64] +
            red[threadIdx.x + 128] + red[threadIdx.x + 192];
        #pragma unroll
        for (int mask = 32; mask; mask >>= 1)
            v += __shfl_xor(v, mask);
    }

    // ---- fence-free fused finish (R6-proven) ----
    if (threadIdx.x == 0) {
        amLast = 0;
        const int ln = blockIdx.x & (NLINE - 1);
        float old = atomicAdd(&g_line[ln].v, v * (1.0f / (float)NROWS));
        asm volatile("" :: "v"(old));        // force vmcnt wait: add completed
        if (atomicAdd(&g_line[ln].cnt, 1) == BPL - 1) {
            if (atomicAdd(&g_master, 1) == NLINE - 1)
                amLast = 1;                  // all lines complete
        }
    }
    __syncthreads();
    if (amLast) {
        if (threadIdx.x < NLINE) {
            float r = __hip_atomic_load(&g_line[threadIdx.x].v,
                                        __ATOMIC_RELAXED, __HIP_MEMORY_SCOPE_AGENT);
            #pragma unroll
            for (int mask = 32; mask; mask >>= 1)
                r += __shfl_xor(r, mask);
            if (threadIdx.x == 0)
                out[0] = r;
            __hip_atomic_store(&g_line[threadIdx.x].v, 0.0f,
                               __ATOMIC_RELAXED, __HIP_MEMORY_SCOPE_AGENT);
            __hip_atomic_store(&g_line[threadIdx.x].cnt, 0,
                               __ATOMIC_RELAXED, __HIP_MEMORY_SCOPE_AGENT);
            if (threadIdx.x == 0)
                __hip_atomic_store(&g_master, 0,
                                   __ATOMIC_RELAXED, __HIP_MEMORY_SCOPE_AGENT);
        }
    }
}

extern "C" void kernel_launch(void* const* d_in, const int* in_sizes, int n_in,
                              void* d_out, int out_size, void* d_ws, size_t ws_size,
                              hipStream_t stream) {
    const float* pred = (const float*)d_in[0];
    const int*   tgt  = (const int*)d_in[1];
    float*       out  = (float*)d_out;
    const int nrows   = in_sizes[1];   // 65536 targets

    OrdinalLoss_main_kernel<<<NBLK, 256, 0, stream>>>(pred, tgt, out, nrows);
}

// Round 11
// 16.645 us; speedup vs baseline: 1.1531x; 1.1531x over previous
//
#include <hip/hip_runtime.h>

#define NROWS  65536
#define NCLS   256
#define NBLK   1024
#define NLINE  64              // partial-sum lines; NBLK/NLINE = 16 blocks each
#define BPL    (NBLK / NLINE)
#define PPW    4               // consecutive packs per wave (16 KB sequential)

typedef float nt_f4 __attribute__((ext_vector_type(4)));

// Device-global finish state. Zero at module load; every call resets it to
// zero => deterministic across graph replays, immune to d_ws poisoning.
// NO fences: ordering comes from completed returning atomics only (R6-proven).
struct __align__(128) Line { float v; int cnt; int pad[30]; };
__device__ Line g_line[NLINE];
__device__ int  g_master;

__global__ __launch_bounds__(256) void OrdinalLoss_main_kernel(
    const float* __restrict__ pred, const int* __restrict__ tgt,
    float* __restrict__ out, int nrows)
{
    const int tid    = blockIdx.x * blockDim.x + threadIdx.x;
    const int lane   = threadIdx.x & 63;
    const int g      = lane >> 4;        // row within 4-row pack
    const int li     = lane & 15;        // lane within 16-lane row group
    const int wave   = tid >> 6;

    float acc = 0.0f;
    const float j0 = (float)(li * 4);

    #define TERM(S0, S1, S2, PV, OFF) {                                     \
        const float d = j0 + (float)(OFF);                                  \
        const float e = __expf(PV);                                         \
        S0 += e;                                                            \
        const float t1 = e * d;                                             \
        S1 += t1;                                                           \
        S2 = fmaf(t1, d, S2); }
    #define PACK16(S0, S1, S2, Q0, Q1, Q2, Q3)                              \
        TERM(S0,S1,S2, Q0[0],   0) TERM(S0,S1,S2, Q0[1],   1)               \
        TERM(S0,S1,S2, Q0[2],   2) TERM(S0,S1,S2, Q0[3],   3)               \
        TERM(S0,S1,S2, Q1[0],  64) TERM(S0,S1,S2, Q1[1],  65)               \
        TERM(S0,S1,S2, Q1[2],  66) TERM(S0,S1,S2, Q1[3],  67)               \
        TERM(S0,S1,S2, Q2[0], 128) TERM(S0,S1,S2, Q2[1], 129)               \
        TERM(S0,S1,S2, Q2[2], 130) TERM(S0,S1,S2, Q2[3], 131)               \
        TERM(S0,S1,S2, Q3[0], 192) TERM(S0,S1,S2, Q3[1], 193)               \
        TERM(S0,S1,S2, Q3[2], 194) TERM(S0,S1,S2, Q3[3], 195)

    #define PT(PTV, T, Q0, Q1, Q2, Q3) {                                    \
        const int q = (T) >> 6, r = (T) & 3;                                \
        const nt_f4 Q = (q==0) ? Q0 : (q==1) ? Q1 : (q==2) ? Q2 : Q3;       \
        const float pv = (r==0) ? Q[0] : (r==1) ? Q[1] : (r==2) ? Q[2] : Q[3]; \
        PTV = (li == (((T) >> 2) & 15)) ? pv : 0.0f; }

    #define REDUCE4(S0, S1, S2, PTV, T)                                     \
        _Pragma("unroll")                                                   \
        for (int m = 8; m; m >>= 1) {                                       \
            S0 += __shfl_xor(S0, m); S1 += __shfl_xor(S1, m);               \
            S2 += __shfl_xor(S2, m); PTV += __shfl_xor(PTV, m);             \
        }                                                                   \
        if (li == 0) {                                                      \
            const float tf = (float)(T);                                    \
            acc += __logf(S0) - PTV                                         \
                 + (S2 - 2.0f * tf * S1 + tf * tf * S0) / S0;               \
        }

    // ---- contiguous-chunk assignment: wave owns PPW consecutive packs ----
    // (16 KB sequential per wave, 64 KB per block: DRAM row-buffer friendly,
    // vs prior grid-stride scatter of 8192 interleaved streams)
    const int npacks = nrows >> 2;
    const int pack0  = wave * PPW;
    #pragma unroll
    for (int i = 0; i < PPW; ++i) {
        const int pack = pack0 + i;
        if (pack >= npacks) break;
        const int row = pack * 4 + g;
        const float* rp = pred + (size_t)row * NCLS + li * 4;
        const nt_f4 a0 = __builtin_nontemporal_load((const nt_f4*)(rp));
        const nt_f4 a1 = __builtin_nontemporal_load((const nt_f4*)(rp + 64));
        const nt_f4 a2 = __builtin_nontemporal_load((const nt_f4*)(rp + 128));
        const nt_f4 a3 = __builtin_nontemporal_load((const nt_f4*)(rp + 192));
        const int    t  = tgt[row];          // 16-lane broadcast, 1 line/wave

        float s0 = 0.0f, s1 = 0.0f, s2 = 0.0f, pt;
        PACK16(s0, s1, s2, a0, a1, a2, a3)
        PT(pt, t, a0, a1, a2, a3)
        REDUCE4(s0, s1, s2, pt, t)
    }
    #undef TERM
    #undef PACK16
    #undef PT
    #undef REDUCE4

    // ---- block reduce ----
    __shared__ float red[256];
    __shared__ int amLast;
    red[threadIdx.x] = acc;
    __syncthreads();
    float v = 0.0f;
    if (threadIdx.x < 64) {
        v = red[threadIdx.x] + red[threadIdx.x + 64] +
            red[threadIdx.x + 128] + red[threadIdx.x + 192];
        #pragma unroll
        for (int mask = 32; mask; mask >>= 1)
            v += __shfl_xor(v, mask);
    }

    // ---- fence-free fused finish (R6-proven) ----
    if (threadIdx.x == 0) {
        amLast = 0;
        const int ln = blockIdx.x & (NLINE - 1);
        float old = atomicAdd(&g_line[ln].v, v * (1.0f / (float)NROWS));
        asm volatile("" :: "v"(old));        // force vmcnt wait: add completed
        if (atomicAdd(&g_line[ln].cnt, 1) == BPL - 1) {
            if (atomicAdd(&g_master, 1) == NLINE - 1)
                amLast = 1;                  // all lines complete
        }
    }
    __syncthreads();
    if (amLast) {
        if (threadIdx.x < NLINE) {
            float r = __hip_atomic_load(&g_line[threadIdx.x].v,
                                        __ATOMIC_RELAXED, __HIP_MEMORY_SCOPE_AGENT);
            #pragma unroll
            for (int mask = 32; mask; mask >>= 1)
                r += __shfl_xor(r, mask);
            if (threadIdx.x == 0)
                out[0] = r;
            __hip_atomic_store(&g_line[threadIdx.x].v, 0.0f,
                               __ATOMIC_RELAXED, __HIP_MEMORY_SCOPE_AGENT);
            __hip_atomic_store(&g_line[threadIdx.x].cnt, 0,
                               __ATOMIC_RELAXED, __HIP_MEMORY_SCOPE_AGENT);
            if (threadIdx.x == 0)
                __hip_atomic_store(&g_master, 0,
                                   __ATOMIC_RELAXED, __HIP_MEMORY_SCOPE_AGENT);
        }
    }
}

extern "C" void kernel_launch(void* const* d_in, const int* in_sizes, int n_in,
                              void* d_out, int out_size, void* d_ws, size_t ws_size,
                              hipStream_t stream) {
    const float* pred = (const float*)d_in[0];
    const int*   tgt  = (const int*)d_in[1];
    float*       out  = (float*)d_out;
    const int nrows   = in_sizes[1];   // 65536 targets

    OrdinalLoss_main_kernel<<<NBLK, 256, 0, stream>>>(pred, tgt, out, nrows);
}

// Round 12
// 16.523 us; speedup vs baseline: 1.1616x; 1.0073x over previous
//
#include <hip/hip_runtime.h>

#define NROWS  65536
#define NCLS   256
#define NBLK   1024
#define NLINE  64              // partial-sum lines; NBLK/NLINE = 16 blocks each
#define BPL    (NBLK / NLINE)
#define WPB    4               // waves per block
#define PPW    4               // packs per wave (block owns WPB*PPW = 16 packs)

typedef float nt_f4 __attribute__((ext_vector_type(4)));

// Device-global finish state. Zero at module load; every call resets it to
// zero => deterministic across graph replays, immune to d_ws poisoning.
// NO fences: ordering comes from completed returning atomics only (R6-proven).
struct __align__(128) Line { float v; int cnt; int pad[30]; };
__device__ Line g_line[NLINE];
__device__ int  g_master;

__global__ __launch_bounds__(256) void OrdinalLoss_main_kernel(
    const float* __restrict__ pred, const int* __restrict__ tgt,
    float* __restrict__ out, int nrows)
{
    const int lane   = threadIdx.x & 63;
    const int g      = lane >> 4;        // row within 4-row pack
    const int li     = lane & 15;        // lane within 16-lane row group
    const int wib    = threadIdx.x >> 6; // wave index within block (0..3)

    float acc = 0.0f;
    const float j0 = (float)(li * 4);

    #define TERM(S0, S1, S2, PV, OFF) {                                     \
        const float d = j0 + (float)(OFF);                                  \
        const float e = __expf(PV);                                         \
        S0 += e;                                                            \
        const float t1 = e * d;                                             \
        S1 += t1;                                                           \
        S2 = fmaf(t1, d, S2); }
    #define PACK16(S0, S1, S2, Q0, Q1, Q2, Q3)                              \
        TERM(S0,S1,S2, Q0[0],   0) TERM(S0,S1,S2, Q0[1],   1)               \
        TERM(S0,S1,S2, Q0[2],   2) TERM(S0,S1,S2, Q0[3],   3)               \
        TERM(S0,S1,S2, Q1[0],  64) TERM(S0,S1,S2, Q1[1],  65)               \
        TERM(S0,S1,S2, Q1[2],  66) TERM(S0,S1,S2, Q1[3],  67)               \
        TERM(S0,S1,S2, Q2[0], 128) TERM(S0,S1,S2, Q2[1], 129)               \
        TERM(S0,S1,S2, Q2[2], 130) TERM(S0,S1,S2, Q2[3], 131)               \
        TERM(S0,S1,S2, Q3[0], 192) TERM(S0,S1,S2, Q3[1], 193)               \
        TERM(S0,S1,S2, Q3[2], 194) TERM(S0,S1,S2, Q3[3], 195)

    #define PT(PTV, T, Q0, Q1, Q2, Q3) {                                    \
        const int q = (T) >> 6, r = (T) & 3;                                \
        const nt_f4 Q = (q==0) ? Q0 : (q==1) ? Q1 : (q==2) ? Q2 : Q3;       \
        const float pv = (r==0) ? Q[0] : (r==1) ? Q[1] : (r==2) ? Q[2] : Q[3]; \
        PTV = (li == (((T) >> 2) & 15)) ? pv : 0.0f; }

    #define REDUCE4(S0, S1, S2, PTV, T)                                     \
        _Pragma("unroll")                                                   \
        for (int m = 8; m; m >>= 1) {                                       \
            S0 += __shfl_xor(S0, m); S1 += __shfl_xor(S1, m);               \
            S2 += __shfl_xor(S2, m); PTV += __shfl_xor(PTV, m);             \
        }                                                                   \
        if (li == 0) {                                                      \
            const float tf = (float)(T);                                    \
            acc += __logf(S0) - PTV                                         \
                 + (S2 - 2.0f * tf * S1 + tf * tf * S0) / S0;               \
        }

    // ---- block-burst mapping: block owns 16 consecutive packs (64 KB);
    // on iteration i its 4 waves read packs base+4i+{0,1,2,3} — one
    // contiguous 16 KB burst per block per step (simultaneous adjacency),
    // vs R11's per-wave chunks whose simultaneous requests were 16 KB apart.
    const int npacks = nrows >> 2;
    const int base   = blockIdx.x * (WPB * PPW);
    #pragma unroll
    for (int i = 0; i < PPW; ++i) {
        const int pack = base + i * WPB + wib;
        if (pack >= npacks) break;
        const int row = pack * 4 + g;
        const float* rp = pred + (size_t)row * NCLS + li * 4;
        const nt_f4 a0 = __builtin_nontemporal_load((const nt_f4*)(rp));
        const nt_f4 a1 = __builtin_nontemporal_load((const nt_f4*)(rp + 64));
        const nt_f4 a2 = __builtin_nontemporal_load((const nt_f4*)(rp + 128));
        const nt_f4 a3 = __builtin_nontemporal_load((const nt_f4*)(rp + 192));
        const int    t  = tgt[row];          // 16-lane broadcast, 1 line/wave

        float s0 = 0.0f, s1 = 0.0f, s2 = 0.0f, pt;
        PACK16(s0, s1, s2, a0, a1, a2, a3)
        PT(pt, t, a0, a1, a2, a3)
        REDUCE4(s0, s1, s2, pt, t)
    }
    #undef TERM
    #undef PACK16
    #undef PT
    #undef REDUCE4

    // ---- block reduce ----
    __shared__ float red[256];
    __shared__ int amLast;
    red[threadIdx.x] = acc;
    __syncthreads();
    float v = 0.0f;
    if (threadIdx.x < 64) {
        v = red[threadIdx.x] + red[threadIdx.x + 64] +
            red[threadIdx.x + 128] + red[threadIdx.x + 192];
        #pragma unroll
        for (int mask = 32; mask; mask >>= 1)
            v += __shfl_xor(v, mask);
    }

    // ---- fence-free fused finish (R6-proven) ----
    if (threadIdx.x == 0) {
        amLast = 0;
        const int ln = blockIdx.x & (NLINE - 1);
        float old = atomicAdd(&g_line[ln].v, v * (1.0f / (float)NROWS));
        asm volatile("" :: "v"(old));        // force vmcnt wait: add completed
        if (atomicAdd(&g_line[ln].cnt, 1) == BPL - 1) {
            if (atomicAdd(&g_master, 1) == NLINE - 1)
                amLast = 1;                  // all lines complete
        }
    }
    __syncthreads();
    if (amLast) {
        if (threadIdx.x < NLINE) {
            float r = __hip_atomic_load(&g_line[threadIdx.x].v,
                                        __ATOMIC_RELAXED, __HIP_MEMORY_SCOPE_AGENT);
            #pragma unroll
            for (int mask = 32; mask; mask >>= 1)
                r += __shfl_xor(r, mask);
            if (threadIdx.x == 0)
                out[0] = r;
            __hip_atomic_store(&g_line[threadIdx.x].v, 0.0f,
                               __ATOMIC_RELAXED, __HIP_MEMORY_SCOPE_AGENT);
            __hip_atomic_store(&g_line[threadIdx.x].cnt, 0,
                               __ATOMIC_RELAXED, __HIP_MEMORY_SCOPE_AGENT);
            if (threadIdx.x == 0)
                __hip_atomic_store(&g_master, 0,
                                   __ATOMIC_RELAXED, __HIP_MEMORY_SCOPE_AGENT);
        }
    }
}

extern "C" void kernel_launch(void* const* d_in, const int* in_sizes, int n_in,
                              void* d_out, int out_size, void* d_ws, size_t ws_size,
                              hipStream_t stream) {
    const float* pred = (const float*)d_in[0];
    const int*   tgt  = (const int*)d_in[1];
    float*       out  = (float*)d_out;
    const int nrows   = in_sizes[1];   // 65536 targets

    OrdinalLoss_main_kernel<<<NBLK, 256, 0, stream>>>(pred, tgt, out, nrows);
}